// Round 1
// baseline (94.196 us; speedup 1.0000x reference)
//
#include <hip/hip_runtime.h>
#include <hip/hip_cooperative_groups.h>
#include <cstdint>
#include <climits>
#include <cmath>

namespace cg = cooperative_groups;

#define ALPHA 0.7f
#define SIGMA 0.1f
#define MIN_MINING_STEP 50

constexpr int TT    = 2048;      // sequence length (fixed by problem)
constexpr int NTH   = 512;       // threads per block
constexpr int EPT   = TT / NTH;  // 4 elements per thread
constexpr int NWAVE = NTH / 64;  // 8 waves per block

// Dual inclusive max-scan over TT elements (EPT consecutive per thread).
// v = forward lane, w = independent reversed lane. exV/exW return the
// exclusive prefix at this thread's first element. ONE internal barrier;
// caller passes a dedicated sW region (2*NWAVE ints) per call so no
// trailing barrier is needed to protect reuse.
__device__ __forceinline__ void dual_maxscan(int (&v)[EPT], int (&w)[EPT],
                                             int& exV, int& exW, int* sW) {
    const int tid = threadIdx.x, lane = tid & 63, wid = tid >> 6;
#pragma unroll
    for (int k = 1; k < EPT; ++k) {
        v[k] = max(v[k], v[k - 1]);
        w[k] = max(w[k], w[k - 1]);
    }
    int tv = v[EPT - 1], tw = w[EPT - 1];
#pragma unroll
    for (int off = 1; off < 64; off <<= 1) {
        int nv = __shfl_up(tv, off), nw = __shfl_up(tw, off);
        if (lane >= off) { tv = max(tv, nv); tw = max(tw, nw); }
    }
    if (lane == 63) { sW[wid] = tv; sW[NWAVE + wid] = tw; }
    __syncthreads();
    int ev = INT_MIN, ew = INT_MIN;
    for (int q = 0; q < wid; ++q) {
        ev = max(ev, sW[q]);
        ew = max(ew, sW[NWAVE + q]);
    }
    int uv = __shfl_up(tv, 1), uw = __shfl_up(tw, 1);
    if (lane > 0) { ev = max(ev, uv); ew = max(ew, uw); }
    exV = ev; exW = ew;
#pragma unroll
    for (int k = 0; k < EPT; ++k) {
        v[k] = max(v[k], ev);
        w[k] = max(w[k], ew);
    }
}

__device__ __forceinline__ float waveRedMin(float v) {
#pragma unroll
    for (int off = 32; off > 0; off >>= 1) v = fminf(v, __shfl_xor(v, off));
    return v;
}
__device__ __forceinline__ float waveRedSum(float v) {
#pragma unroll
    for (int off = 32; off > 0; off >>= 1) v += __shfl_xor(v, off);
    return v;
}

// One block per abnormal row. sigmoid+crop-mean -> scan-based mining ->
// scan-based nearest-anchor distance -> splat -> min-max norm -> BCE ->
// per-row partial, then cooperative grid-sync and block 0 does the final
// 32-wide reduce (replaces the former second kernel dispatch).
__global__ __launch_bounds__(NTH) void glance_fused(
    const float* __restrict__ scores,       // (B*C, T)
    const int*   __restrict__ point_label,  // (B, T)
    const int*   __restrict__ seqlen,       // (B,)
    const int*   __restrict__ step_p,       // (1,)
    float*       __restrict__ partial,      // (nb,) in workspace
    float*       __restrict__ out,          // (1,)
    int C, float invN)
{
    __shared__ float sS[TT];           // probs (crop-mean of sigmoids)
    __shared__ int   sM[TT];           // anchors -> mask -> (reused) bwd distance
    __shared__ int   sW[6 * NWAVE];    // 3 scan calls x (2*NWAVE) rotating regions
    __shared__ float sRmin[NWAVE];
    __shared__ float sRsum[NWAVE];

    const int b = blockIdx.x, tid = threadIdx.x, lane = tid & 63, wid = tid >> 6;

    // ---- load + sigmoid + crop mean (float4/int4 vectorized; 1 iter/thread) ----
    const float invC = 1.0f / (float)C;
    for (int q4 = tid; q4 < TT / 4; q4 += NTH) {
        float4 acc = make_float4(0.f, 0.f, 0.f, 0.f);
        for (int c = 0; c < C; ++c) {
            const float4 x = ((const float4*)(scores + ((size_t)(b * C + c)) * TT))[q4];
            acc.x += 1.0f / (1.0f + __expf(-x.x));
            acc.y += 1.0f / (1.0f + __expf(-x.y));
            acc.z += 1.0f / (1.0f + __expf(-x.z));
            acc.w += 1.0f / (1.0f + __expf(-x.w));
        }
        const int4 p = ((const int4*)(point_label + (size_t)b * TT))[q4];
        const int t = q4 * 4;
        sS[t + 0] = acc.x * invC;  sM[t + 0] = (p.x > 0) ? 1 : 0;
        sS[t + 1] = acc.y * invC;  sM[t + 1] = (p.y > 0) ? 1 : 0;
        sS[t + 2] = acc.z * invC;  sM[t + 2] = (p.z > 0) ? 1 : 0;
        sS[t + 3] = acc.w * invC;  sM[t + 3] = (p.w > 0) ? 1 : 0;
    }
    const int stepv = step_p[0];
    const int vlen  = seqlen[b];
    __syncthreads();                                          // B1

    const int j0 = tid * EPT;

    // ---- mining (both directions fused into dual scans) ----
    // g[j] = lastAnchorBefore(j) >= 0 && lastFail(<=j) <= lastAnchorBefore(j)
    if (stepv >= MIN_MINING_STEP) {
        // pass 1: last-anchor-index scan. v: t=j (fwd); w: t=TT-1-j (bwd coords)
        int va[EPT], wa[EPT]; int exA, exB;
#pragma unroll
        for (int k = 0; k < EPT; ++k) {
            const int j = j0 + k;
            va[k] = sM[j] ? j : -1;
            wa[k] = sM[TT - 1 - j] ? j : -1;
        }
        dual_maxscan(va, wa, exA, exB, sW);                   // B2

        // pass 2: last-fail-index scan (cond vs segment anchor, per element)
        int vf[EPT], wf[EPT]; int exF, exG;
        int qf[EPT], qb[EPT];
#pragma unroll
        for (int k = 0; k < EPT; ++k) {
            const int j  = j0 + k;
            const int qF = (k == 0) ? exA : va[k - 1];   // anchor strictly before j
            const int qB = (k == 0) ? exB : wa[k - 1];
            qf[k] = qF; qb[k] = qB;
            bool cF = false, cB = false;
            if (qF >= 0) cF = sS[j]          >= ALPHA * sS[qF];
            if (qB >= 0) cB = sS[TT - 1 - j] >= ALPHA * sS[TT - 1 - qB];
            vf[k] = cF ? -1 : j;
            wf[k] = cB ? -1 : j;
        }
        dual_maxscan(vf, wf, exF, exG, sW + 2 * NWAVE);       // B3

        // mask writes (benign 1-races; scan barrier ordered the sS/sM reads)
#pragma unroll
        for (int k = 0; k < EPT; ++k) {
            const int j = j0 + k;
            const bool gF = (qf[k] >= 0) && (vf[k] <= qf[k]) && (j < vlen);
            const bool gB = (qb[k] >= 0) && (wf[k] <= qb[k]);
            if (gF) sM[j] = 1;
            if (gB) sM[TT - 1 - j] = 1;
        }
        __syncthreads();                                      // B4
    }

    // ---- nearest-mask distance via dual scan ----
    int vn[EPT], wn[EPT]; int exN, exO;
#pragma unroll
    for (int k = 0; k < EPT; ++k) {
        const int j = j0 + k;
        vn[k] = sM[j] ? j : -1;
        wn[k] = sM[TT - 1 - j] ? j : -1;
    }
    dual_maxscan(vn, wn, exN, exO, sW + 4 * NWAVE);           // B5

    // exchange bwd distance (next mask at/after t) through sM
    // (sM input reads all happened before B5; these writes are after it)
#pragma unroll
    for (int k = 0; k < EPT; ++k) {
        const int j  = j0 + k;
        const int dB = (wn[k] >= 0) ? min(j - wn[k], 4096) : 4096;
        sM[TT - 1 - j] = dB;
    }
    // any-mask flag broadcast via sW
    if (tid == NTH - 1) sW[0] = (vn[EPT - 1] >= 0) ? 1 : 0;
    __syncthreads();                                          // B6
    const bool any = (sW[0] != 0);

    // ---- temp[i] = exp(-K*minDist^2); per-anchor norm term m_p <= 2e-22 ignored.
    // tmax == 1 exactly when any mask exists (dist 0 at a masked position).
    const float KK = 2.0f / ((float)(TT - 1) * (float)(TT - 1) * SIGMA * SIGMA);
    float tempv[EPT];
    float tmn = INFINITY;
#pragma unroll
    for (int k = 0; k < EPT; ++k) {
        const int j  = j0 + k;
        const int dF = (vn[k] >= 0) ? min(j - vn[k], 4096) : 4096;
        const int d  = min(dF, sM[j]);
        const float tv = __expf(-KK * (float)(d * d));
        tempv[k] = tv;
        tmn = fminf(tmn, tv);
    }
    tmn = waveRedMin(tmn);
    if (lane == 0) sRmin[wid] = tmn;
    __syncthreads();                                          // B7
    tmn = sRmin[0];
    for (int w = 1; w < NWAVE; ++w) tmn = fminf(tmn, sRmin[w]);

    // ---- rendered + BCE partial ----
    const bool norm = any && (tmn < 1.0f);
    const float inv = norm ? 1.0f / (1.0f - tmn) : 0.0f;
    float lsum = 0.0f;
#pragma unroll
    for (int k = 0; k < EPT; ++k) {
        float r = 0.0f;
        if (any) r = norm ? (tempv[k] - tmn) * inv : tempv[k];
        const float s = sS[j0 + k];
        lsum += -(r * __logf(s) + (1.0f - r) * __logf(1.0f - s));
    }
    lsum = waveRedSum(lsum);
    if (lane == 0) sRsum[wid] = lsum;   // separate region: no race with sRmin reads
    __syncthreads();                                          // B8
    if (tid == 0) {
        float tot = 0.0f;
        for (int w = 0; w < NWAVE; ++w) tot += sRsum[w];
        partial[b] = tot;
        __threadfence();                // device-scope release of partial[b]
    }

    // ---- grid-wide sync, then block 0 does the (bit-identical) final reduce ----
    cg::this_grid().sync();

    if (b == 0 && tid < 64) {
        const int nb = (int)gridDim.x;
        float v = (tid < nb) ? partial[tid] : 0.0f;
#pragma unroll
        for (int off = 32; off > 0; off >>= 1) v += __shfl_down(v, off);
        if (tid == 0) out[0] = v * invN;
    }
}

extern "C" void kernel_launch(void* const* d_in, const int* in_sizes, int n_in,
                              void* d_out, int out_size, void* d_ws, size_t ws_size,
                              hipStream_t stream) {
    (void)n_in; (void)out_size; (void)ws_size;
    const float* scores      = (const float*)d_in[0];
    // d_in[1] = labels (unused by the reference computation)
    const int*   point_label = (const int*)d_in[2];
    const int*   seqlen      = (const int*)d_in[3];
    const int*   step_p      = (const int*)d_in[4];

    const int B  = in_sizes[1];            // labels has B elements (64)
    const int T  = in_sizes[2] / B;        // 2048 (kernel assumes TT==2048)
    const int C  = in_sizes[0] / (B * T);  // 2
    const int nb = B / 2;                  // 32

    float* partial = (float*)d_ws;
    float* outp    = (float*)d_out;
    float  invN    = 1.0f / (float)(nb * T);

    void* args[] = { (void*)&scores, (void*)&point_label, (void*)&seqlen,
                     (void*)&step_p, (void*)&partial, (void*)&outp,
                     (void*)&C, (void*)&invN };
    hipLaunchCooperativeKernel((const void*)glance_fused, dim3(nb), dim3(NTH),
                               args, 0, stream);
}

// Round 2
// 67.305 us; speedup vs baseline: 1.3995x; 1.3995x over previous
//
#include <hip/hip_runtime.h>
#include <cstdint>
#include <climits>
#include <cmath>

#define ALPHA 0.7f
#define SIGMA 0.1f
#define MIN_MINING_STEP 50

constexpr int TT    = 2048;      // sequence length (fixed by problem)
constexpr int NTH   = 512;       // threads per block
constexpr int EPT   = TT / NTH;  // 4 elements per thread
constexpr int NWAVE = NTH / 64;  // 8 waves per block

constexpr uint32_t MAGIC = 0x9E3779B9u;  // 4 distinct bytes: no byte-pattern
                                         // poison fill can forge this flag.

// Dual inclusive max-scan over TT elements (EPT consecutive per thread).
// v = forward lane, w = independent reversed lane. exV/exW return the
// exclusive prefix at this thread's first element. ONE internal barrier;
// caller passes a dedicated sW region (2*NWAVE ints) per call so no
// trailing barrier is needed to protect reuse.
__device__ __forceinline__ void dual_maxscan(int (&v)[EPT], int (&w)[EPT],
                                             int& exV, int& exW, int* sW) {
    const int tid = threadIdx.x, lane = tid & 63, wid = tid >> 6;
#pragma unroll
    for (int k = 1; k < EPT; ++k) {
        v[k] = max(v[k], v[k - 1]);
        w[k] = max(w[k], w[k - 1]);
    }
    int tv = v[EPT - 1], tw = w[EPT - 1];
#pragma unroll
    for (int off = 1; off < 64; off <<= 1) {
        int nv = __shfl_up(tv, off), nw = __shfl_up(tw, off);
        if (lane >= off) { tv = max(tv, nv); tw = max(tw, nw); }
    }
    if (lane == 63) { sW[wid] = tv; sW[NWAVE + wid] = tw; }
    __syncthreads();
    int ev = INT_MIN, ew = INT_MIN;
    for (int q = 0; q < wid; ++q) {
        ev = max(ev, sW[q]);
        ew = max(ew, sW[NWAVE + q]);
    }
    int uv = __shfl_up(tv, 1), uw = __shfl_up(tw, 1);
    if (lane > 0) { ev = max(ev, uv); ew = max(ew, uw); }
    exV = ev; exW = ew;
#pragma unroll
    for (int k = 0; k < EPT; ++k) {
        v[k] = max(v[k], ev);
        w[k] = max(w[k], ew);
    }
}

__device__ __forceinline__ float waveRedMin(float v) {
#pragma unroll
    for (int off = 32; off > 0; off >>= 1) v = fminf(v, __shfl_xor(v, off));
    return v;
}
__device__ __forceinline__ float waveRedSum(float v) {
#pragma unroll
    for (int off = 32; off > 0; off >>= 1) v += __shfl_xor(v, off);
    return v;
}

// One block per abnormal row. sigmoid+crop-mean -> scan-based mining ->
// scan-based nearest-anchor distance -> splat -> min-max norm -> BCE ->
// per-row partial. Final reduce folded in: each block release-stores a
// MAGIC flag after its partial; block 0's first wave acquire-spins on all
// flags and replays the bit-identical 64-lane shuffle reduce. One-way
// dependency (block 0 waits; blocks 1..nb-1 never wait) -> deadlock-free
// under any scheduling; device-scope atomics cross XCD L2s.
__global__ __launch_bounds__(NTH) void glance_fused(
    const float* __restrict__ scores,       // (B*C, T)
    const int*   __restrict__ point_label,  // (B, T)
    const int*   __restrict__ seqlen,       // (B,)
    const int*   __restrict__ step_p,       // (1,)
    float*       __restrict__ partial,      // (nb,) in workspace
    uint32_t*    __restrict__ flags,        // (nb,) in workspace
    float*       __restrict__ out,          // (1,)
    int C, float invN)
{
    __shared__ float sS[TT];           // probs (crop-mean of sigmoids)
    __shared__ int   sM[TT];           // anchors -> mask -> (reused) bwd distance
    __shared__ int   sW[6 * NWAVE];    // 3 scan calls x (2*NWAVE) rotating regions
    __shared__ float sRmin[NWAVE];
    __shared__ float sRsum[NWAVE];

    const int b = blockIdx.x, tid = threadIdx.x, lane = tid & 63, wid = tid >> 6;

    // ---- load + sigmoid + crop mean (float4/int4 vectorized; 1 iter/thread) ----
    const float invC = 1.0f / (float)C;
    for (int q4 = tid; q4 < TT / 4; q4 += NTH) {
        float4 acc = make_float4(0.f, 0.f, 0.f, 0.f);
        for (int c = 0; c < C; ++c) {
            const float4 x = ((const float4*)(scores + ((size_t)(b * C + c)) * TT))[q4];
            acc.x += 1.0f / (1.0f + __expf(-x.x));
            acc.y += 1.0f / (1.0f + __expf(-x.y));
            acc.z += 1.0f / (1.0f + __expf(-x.z));
            acc.w += 1.0f / (1.0f + __expf(-x.w));
        }
        const int4 p = ((const int4*)(point_label + (size_t)b * TT))[q4];
        const int t = q4 * 4;
        sS[t + 0] = acc.x * invC;  sM[t + 0] = (p.x > 0) ? 1 : 0;
        sS[t + 1] = acc.y * invC;  sM[t + 1] = (p.y > 0) ? 1 : 0;
        sS[t + 2] = acc.z * invC;  sM[t + 2] = (p.z > 0) ? 1 : 0;
        sS[t + 3] = acc.w * invC;  sM[t + 3] = (p.w > 0) ? 1 : 0;
    }
    const int stepv = step_p[0];
    const int vlen  = seqlen[b];
    __syncthreads();                                          // B1

    const int j0 = tid * EPT;

    // ---- mining (both directions fused into dual scans) ----
    // g[j] = lastAnchorBefore(j) >= 0 && lastFail(<=j) <= lastAnchorBefore(j)
    if (stepv >= MIN_MINING_STEP) {
        // pass 1: last-anchor-index scan. v: t=j (fwd); w: t=TT-1-j (bwd coords)
        int va[EPT], wa[EPT]; int exA, exB;
#pragma unroll
        for (int k = 0; k < EPT; ++k) {
            const int j = j0 + k;
            va[k] = sM[j] ? j : -1;
            wa[k] = sM[TT - 1 - j] ? j : -1;
        }
        dual_maxscan(va, wa, exA, exB, sW);                   // B2

        // pass 2: last-fail-index scan (cond vs segment anchor, per element)
        int vf[EPT], wf[EPT]; int exF, exG;
        int qf[EPT], qb[EPT];
#pragma unroll
        for (int k = 0; k < EPT; ++k) {
            const int j  = j0 + k;
            const int qF = (k == 0) ? exA : va[k - 1];   // anchor strictly before j
            const int qB = (k == 0) ? exB : wa[k - 1];
            qf[k] = qF; qb[k] = qB;
            bool cF = false, cB = false;
            if (qF >= 0) cF = sS[j]          >= ALPHA * sS[qF];
            if (qB >= 0) cB = sS[TT - 1 - j] >= ALPHA * sS[TT - 1 - qB];
            vf[k] = cF ? -1 : j;
            wf[k] = cB ? -1 : j;
        }
        dual_maxscan(vf, wf, exF, exG, sW + 2 * NWAVE);       // B3

        // mask writes (benign 1-races; scan barrier ordered the sS/sM reads)
#pragma unroll
        for (int k = 0; k < EPT; ++k) {
            const int j = j0 + k;
            const bool gF = (qf[k] >= 0) && (vf[k] <= qf[k]) && (j < vlen);
            const bool gB = (qb[k] >= 0) && (wf[k] <= qb[k]);
            if (gF) sM[j] = 1;
            if (gB) sM[TT - 1 - j] = 1;
        }
        __syncthreads();                                      // B4
    }

    // ---- nearest-mask distance via dual scan ----
    int vn[EPT], wn[EPT]; int exN, exO;
#pragma unroll
    for (int k = 0; k < EPT; ++k) {
        const int j = j0 + k;
        vn[k] = sM[j] ? j : -1;
        wn[k] = sM[TT - 1 - j] ? j : -1;
    }
    dual_maxscan(vn, wn, exN, exO, sW + 4 * NWAVE);           // B5

    // exchange bwd distance (next mask at/after t) through sM
    // (sM input reads all happened before B5; these writes are after it)
#pragma unroll
    for (int k = 0; k < EPT; ++k) {
        const int j  = j0 + k;
        const int dB = (wn[k] >= 0) ? min(j - wn[k], 4096) : 4096;
        sM[TT - 1 - j] = dB;
    }
    // any-mask flag broadcast via sW
    if (tid == NTH - 1) sW[0] = (vn[EPT - 1] >= 0) ? 1 : 0;
    __syncthreads();                                          // B6
    const bool any = (sW[0] != 0);

    // ---- temp[i] = exp(-K*minDist^2); per-anchor norm term m_p <= 2e-22 ignored.
    // tmax == 1 exactly when any mask exists (dist 0 at a masked position).
    const float KK = 2.0f / ((float)(TT - 1) * (float)(TT - 1) * SIGMA * SIGMA);
    float tempv[EPT];
    float tmn = INFINITY;
#pragma unroll
    for (int k = 0; k < EPT; ++k) {
        const int j  = j0 + k;
        const int dF = (vn[k] >= 0) ? min(j - vn[k], 4096) : 4096;
        const int d  = min(dF, sM[j]);
        const float tv = __expf(-KK * (float)(d * d));
        tempv[k] = tv;
        tmn = fminf(tmn, tv);
    }
    tmn = waveRedMin(tmn);
    if (lane == 0) sRmin[wid] = tmn;
    __syncthreads();                                          // B7
    tmn = sRmin[0];
    for (int w = 1; w < NWAVE; ++w) tmn = fminf(tmn, sRmin[w]);

    // ---- rendered + BCE partial ----
    const bool norm = any && (tmn < 1.0f);
    const float inv = norm ? 1.0f / (1.0f - tmn) : 0.0f;
    float lsum = 0.0f;
#pragma unroll
    for (int k = 0; k < EPT; ++k) {
        float r = 0.0f;
        if (any) r = norm ? (tempv[k] - tmn) * inv : tempv[k];
        const float s = sS[j0 + k];
        lsum += -(r * __logf(s) + (1.0f - r) * __logf(1.0f - s));
    }
    lsum = waveRedSum(lsum);
    if (lane == 0) sRsum[wid] = lsum;   // separate region: no race with sRmin reads
    __syncthreads();                                          // B8
    if (tid == 0) {
        float tot = 0.0f;
        for (int w = 0; w < NWAVE; ++w) tot += sRsum[w];
        partial[b] = tot;
        // release: partial[b] visible (device scope) before flag observed
        __hip_atomic_store(&flags[b], MAGIC, __ATOMIC_RELEASE,
                           __HIP_MEMORY_SCOPE_AGENT);
    }

    // ---- folded final reduce: block 0, first wave only ----
    if (b == 0 && tid < 64) {
        const int nb = (int)gridDim.x;
        float v = 0.0f;
        if (tid < nb) {
            // one-way wait: blocks 1..nb-1 never wait on anyone -> no deadlock
            while (__hip_atomic_load(&flags[tid], __ATOMIC_ACQUIRE,
                                     __HIP_MEMORY_SCOPE_AGENT) != MAGIC) { }
            v = partial[tid];
        }
#pragma unroll
        for (int off = 32; off > 0; off >>= 1) v += __shfl_down(v, off);
        if (tid == 0) out[0] = v * invN;
    }
}

extern "C" void kernel_launch(void* const* d_in, const int* in_sizes, int n_in,
                              void* d_out, int out_size, void* d_ws, size_t ws_size,
                              hipStream_t stream) {
    (void)n_in; (void)out_size; (void)ws_size;
    const float* scores      = (const float*)d_in[0];
    // d_in[1] = labels (unused by the reference computation)
    const int*   point_label = (const int*)d_in[2];
    const int*   seqlen      = (const int*)d_in[3];
    const int*   step_p      = (const int*)d_in[4];

    const int B  = in_sizes[1];            // labels has B elements (64)
    const int T  = in_sizes[2] / B;        // 2048 (kernel assumes TT==2048)
    const int C  = in_sizes[0] / (B * T);  // 2
    const int nb = B / 2;                  // 32

    float*    partial = (float*)d_ws;                          // 32 floats
    uint32_t* flags   = (uint32_t*)((char*)d_ws + 256);        // 32 flags

    glance_fused<<<nb, NTH, 0, stream>>>(scores, point_label, seqlen, step_p,
                                         partial, flags, (float*)d_out, C,
                                         1.0f / (float)(nb * T));
}